// Round 1
// baseline (102.545 us; speedup 1.0000x reference)
//
#include <hip/hip_runtime.h>

#define NUM_GRAPHS 128
#define NUM_T 64
#define NUM_S 64
#define CHUNK 512

// Kernel 1: segment starts via binary search over the sorted batch array.
// starts[g] = first index n with batch[n] >= g, for g in [0, NUM_GRAPHS].
__global__ void seg_starts_kernel(const int* __restrict__ batch, int n,
                                  int* __restrict__ starts) {
    int g = threadIdx.x;
    if (g > NUM_GRAPHS) return;
    int lo = 0, hi = n;
    while (lo < hi) {
        int mid = (lo + hi) >> 1;
        if (batch[mid] < g) lo = mid + 1; else hi = mid;
    }
    starts[g] = lo;
}

// Kernel 2: one block per (graph, s-half). 512 threads:
//   t  = tid & 63   (theta index)
//   sg = tid >> 6   (0..7) -> this thread owns s = shalf*32 + sg*4 + {0..3}
// Each thread accumulates its 4 (s,t) outputs over all points of the graph.
// sigmoid(200*(lin - nh)) = 1 / (1 + exp2(K*nh - K*lin)), K = 200*log2(e).
__global__ __launch_bounds__(512, 2) void ect_kernel(
    const float2* __restrict__ x, const float* __restrict__ v,
    const float* __restrict__ lin, const int* __restrict__ starts,
    float* __restrict__ out)
{
    constexpr float K = 288.539008177792681471984936f; // 200 * log2(e)
    const int g = blockIdx.x;
    const int shalf = blockIdx.y;
    const int tid = (int)threadIdx.x;
    const int t = tid & 63;
    const int sg = tid >> 6;
    const int s0 = shalf * 32 + sg * 4;

    const float kv0 = K * v[2 * t];
    const float kv1 = K * v[2 * t + 1];
    const float c0 = K * lin[s0 + 0];
    const float c1 = K * lin[s0 + 1];
    const float c2 = K * lin[s0 + 2];
    const float c3 = K * lin[s0 + 3];

    float acc0 = 0.f, acc1 = 0.f, acc2 = 0.f, acc3 = 0.f;

    const int nbeg = starts[g];
    const int nend = starts[g + 1];

    __shared__ float2 xs[CHUNK];

    for (int base = nbeg; base < nend; base += CHUNK) {
        const int cnt = min(CHUNK, nend - base);
        __syncthreads();
        for (int i = tid; i < cnt; i += 512) xs[i] = x[base + i];
        __syncthreads();
        #pragma unroll 2
        for (int i = 0; i < cnt; ++i) {
            const float2 p = xs[i];                  // LDS broadcast read
            const float a = fmaf(p.x, kv0, p.y * kv1); // = K * nh
            // 4 independent sigmoid chains for ILP
            const float e0 = __builtin_amdgcn_exp2f(a - c0);
            const float e1 = __builtin_amdgcn_exp2f(a - c1);
            const float e2 = __builtin_amdgcn_exp2f(a - c2);
            const float e3 = __builtin_amdgcn_exp2f(a - c3);
            acc0 += __builtin_amdgcn_rcpf(1.0f + e0);
            acc1 += __builtin_amdgcn_rcpf(1.0f + e1);
            acc2 += __builtin_amdgcn_rcpf(1.0f + e2);
            acc3 += __builtin_amdgcn_rcpf(1.0f + e3);
        }
    }

    float* o = out + ((size_t)g * NUM_S + s0) * NUM_T + t;
    o[0 * NUM_T] = acc0;
    o[1 * NUM_T] = acc1;
    o[2 * NUM_T] = acc2;
    o[3 * NUM_T] = acc3;
}

extern "C" void kernel_launch(void* const* d_in, const int* in_sizes, int n_in,
                              void* d_out, int out_size, void* d_ws, size_t ws_size,
                              hipStream_t stream) {
    const float2* x   = (const float2*)d_in[0];   // [N,2] f32
    const float*  v   = (const float*)d_in[1];    // [64,2] f32
    const float*  lin = (const float*)d_in[2];    // [64] f32
    const int*    bat = (const int*)d_in[3];      // [N] i32 (sorted)
    float* out = (float*)d_out;                   // [128,64,64] f32
    const int n = in_sizes[3];

    int* starts = (int*)d_ws;                     // NUM_GRAPHS+1 ints

    seg_starts_kernel<<<1, 256, 0, stream>>>(bat, n, starts);
    ect_kernel<<<dim3(NUM_GRAPHS, 2), 512, 0, stream>>>(x, v, lin, starts, out);
}